// Round 4
// baseline (595.994 us; speedup 1.0000x reference)
//
#include <hip/hip_runtime.h>

#define SEQ 2048
#define NROWS 8192            // 4 * 2048
#define NH 16
#define DHEAD 64
#define QLD 3072              // q,k,v concatenated columns

typedef float f32x4 __attribute__((ext_vector_type(4)));
typedef __bf16 bf16x8 __attribute__((ext_vector_type(8)));

__device__ __forceinline__ unsigned short f2bf(float f) {
  union { float f; unsigned u; } v; v.f = f;
  unsigned r = v.u + 0x7fffu + ((v.u >> 16) & 1u);
  return (unsigned short)(r >> 16);
}

__device__ __forceinline__ void gl16(const void* g, void* l) {
  __builtin_amdgcn_global_load_lds((const __attribute__((address_space(1))) void*)g,
                                   (__attribute__((address_space(3))) void*)l, 16, 0, 0);
}

__device__ __forceinline__ float gelu_f(float x) {
  float t = 0.7978845608028654f * (x + 0.044715f * x * x * x);
  float e = __expf(2.0f * t);
  float th = 1.0f - 2.0f / (e + 1.0f);   // tanh(t), saturates cleanly
  return 0.5f * x * (1.0f + th);
}

#define CVTPK(dst, lo, hi) asm("v_cvt_pk_bf16_f32 %0, %1, %2" : "=v"(dst) : "v"(lo), "v"(hi))

#if __has_builtin(__builtin_amdgcn_permlane32_swap)
#define P32SWAP(a, b, x, y) { auto _t = __builtin_amdgcn_permlane32_swap((a), (b), false, false); (x) = _t[0]; (y) = _t[1]; }
#else
#define P32SWAP(a, b, x, y) { unsigned _as = (unsigned)__shfl_xor((int)(a), 32, 64); \
  unsigned _bs = (unsigned)__shfl_xor((int)(b), 32, 64); \
  (x) = (l < 32) ? (a) : _bs; (y) = (l < 32) ? _as : (b); }
#endif
#if __has_builtin(__builtin_amdgcn_permlane16_swap)
#define P16SWAP(a, b, x, y) { auto _t = __builtin_amdgcn_permlane16_swap((a), (b), false, false); (x) = _t[0]; (y) = _t[1]; }
#else
#define P16SWAP(a, b, x, y) { unsigned _as = (unsigned)__shfl_xor((int)(a), 16, 64); \
  unsigned _bs = (unsigned)__shfl_xor((int)(b), 16, 64); \
  (x) = (l & 16) ? _bs : (a); (y) = (l & 16) ? (b) : _as; }
#endif

#define MEMFENCE asm volatile("" ::: "memory")
#define BAR() do { MEMFENCE; __builtin_amdgcn_s_barrier(); MEMFENCE; } while (0)
#define WAIT_LGKM0 asm volatile("s_waitcnt lgkmcnt(0)" ::: "memory")
#define WAIT_VM0 asm volatile("s_waitcnt vmcnt(0)" ::: "memory")

// ---------------- transpose + fp32->bf16 convert: Wt[n][k] = W[k][n] ----------------
__global__ __launch_bounds__(256) void transpose_cvt(const float* __restrict__ W,
                                                     unsigned short* __restrict__ Wt,
                                                     int K, int N) {
  __shared__ float tile[32][33];
  const int tx = threadIdx.x, ty = threadIdx.y;
  const int n0 = blockIdx.x * 32, k0 = blockIdx.y * 32;
#pragma unroll
  for (int i = ty; i < 32; i += 8)
    tile[i][tx] = W[(size_t)(k0 + i) * N + n0 + tx];
  __syncthreads();
#pragma unroll
  for (int i = ty; i < 32; i += 8)
    Wt[(size_t)(n0 + i) * K + k0 + tx] = f2bf(tile[tx][i]);
}

__global__ __launch_bounds__(256) void concat_bias(const float* __restrict__ bq,
                                                   const float* __restrict__ bk,
                                                   const float* __restrict__ bv,
                                                   float* __restrict__ dst) {
  int i = blockIdx.x * 256 + threadIdx.x;
  if (i < 1024) dst[i] = bq[i];
  else if (i < 2048) dst[i] = bk[i - 1024];
  else if (i < 3072) dst[i] = bv[i - 2048];
}

// ---------------- LayerNorm: fp32 in -> bf16 out, one block per 1024-row ----------------
__global__ __launch_bounds__(256) void layernorm_k(const float* __restrict__ x,
                                                   const float* __restrict__ g,
                                                   const float* __restrict__ b,
                                                   unsigned short* __restrict__ out) {
  const int row = blockIdx.x, tid = threadIdx.x;
  const float4 v = reinterpret_cast<const float4*>(x + (size_t)row * 1024)[tid];
  float s = v.x + v.y + v.z + v.w;
  float s2 = v.x * v.x + v.y * v.y + v.z * v.z + v.w * v.w;
#pragma unroll
  for (int d = 1; d < 64; d <<= 1) { s += __shfl_xor(s, d, 64); s2 += __shfl_xor(s2, d, 64); }
  __shared__ float ls[4], ls2[4];
  const int w = tid >> 6;
  if ((tid & 63) == 0) { ls[w] = s; ls2[w] = s2; }
  __syncthreads();
  s = ls[0] + ls[1] + ls[2] + ls[3];
  s2 = ls2[0] + ls2[1] + ls2[2] + ls2[3];
  const float mu = s * (1.0f / 1024.0f);
  const float var = s2 * (1.0f / 1024.0f) - mu * mu;
  const float rstd = rsqrtf(var + 1e-6f);
  const float4 gv = reinterpret_cast<const float4*>(g)[tid];
  const float4 bv = reinterpret_cast<const float4*>(b)[tid];
  ushort4 o;
  o.x = f2bf((v.x - mu) * rstd * gv.x + bv.x);
  o.y = f2bf((v.y - mu) * rstd * gv.y + bv.y);
  o.z = f2bf((v.z - mu) * rstd * gv.z + bv.z);
  o.w = f2bf((v.w - mu) * rstd * gv.w + bv.w);
  reinterpret_cast<ushort4*>(out + (size_t)row * 1024)[tid] = o;
}

enum { EP_BIAS = 1, EP_RES = 2, EP_GELU = 4, EP_BF16 = 8, EP_QSCALE = 16 };

// ---------------- Phase-pipelined GEMM: C[M,N] = A[M,K] * Bt[N,K]^T + epilogue ----------
// BN=256 always, 512 threads (8 waves, 2M x 4N). BM=256 (wave 128x64) or 128 (wave 64x64).
// All of tile t+1's global_load_lds issued at phase 0 of tile t; single vmcnt(0) at
// phase 3 => loads get ~full-tile cover (T3/T4). XOR-swizzled LDS (T2), raw barriers,
// setprio (T5), XCD-aware block order (T1).
template <int BM, int E>
__global__ __launch_bounds__(512, 2) void gemm8_k(const unsigned short* __restrict__ A,
                                                  const unsigned short* __restrict__ Bt,
                                                  const float* __restrict__ bias,
                                                  const float* __restrict__ resid,
                                                  void* __restrict__ out,
                                                  int M, int N, int K) {
  constexpr int BN = 256;
  constexpr int WM = BM / 2;     // wave-tile M
  constexpr int MI = WM / 16;    // 8 or 4
  constexpr int MQ = MI / 2;
  __shared__ __align__(16) unsigned short As[2][BM * 64];
  __shared__ __align__(16) unsigned short Bs[2][BN * 64];

  const int tid = threadIdx.x;
  const int l = tid & 63, w = tid >> 6;
  const int lr = l & 15, lg = l >> 4;
  const int wr = w >> 2, wc = w & 3;

  // T1: bijective XCD chunking (nwg % 8 == 0 for all our grids); consecutive lin
  // within a chunk share bm (A-panel stays in that XCD's L2).
  const int gx = gridDim.x;
  const int nwg = gx * gridDim.y;
  int lin = blockIdx.y * gx + blockIdx.x;
  lin = (lin & 7) * (nwg >> 3) + (lin >> 3);
  const int bn = lin % gx, bm = lin / gx;

  const unsigned short* Ab = A + (size_t)(bm * BM) * K;
  const unsigned short* Bb = Bt + (size_t)(bn * BN) * K;

  const int srow8 = l >> 3;
  const int slot = (l & 7) ^ (srow8 & 7);
  auto stA = [&](int buf, int t, int s) {
    gl16((const char*)(Ab + (size_t)(s * 8 + srow8) * K + t * 64) + slot * 16,
         (char*)(&As[buf][0]) + s * 1024 + l * 16);
  };
  auto stB = [&](int buf, int t, int s) {
    gl16((const char*)(Bb + (size_t)(s * 8 + srow8) * K + t * 64) + slot * 16,
         (char*)(&Bs[buf][0]) + s * 1024 + l * 16);
  };
  auto stageAll = [&](int buf, int t) {
    stA(buf, t, w); stA(buf, t, 8 + w);
    if (BM == 256) { stA(buf, t, 16 + w); stA(buf, t, 24 + w); }
    stB(buf, t, w); stB(buf, t, 8 + w); stB(buf, t, 16 + w); stB(buf, t, 24 + w);
  };
  auto rdA = [&](int buf, int r, int ks) {
    return *reinterpret_cast<const bf16x8*>(
        (const char*)(&As[buf][0]) + r * 128 + (((ks << 2) + lg) ^ (r & 7)) * 16);
  };
  auto rdB = [&](int buf, int r, int ks) {
    return *reinterpret_cast<const bf16x8*>(
        (const char*)(&Bs[buf][0]) + r * 128 + (((ks << 2) + lg) ^ (r & 7)) * 16);
  };

  f32x4 acc[MI][4];
#pragma unroll
  for (int m = 0; m < MI; ++m)
#pragma unroll
    for (int n = 0; n < 4; ++n) acc[m][n] = 0.0f;

  const int NK = K >> 6;
  stageAll(0, 0);
  WAIT_VM0;
  BAR();

#pragma unroll 2
  for (int kt = 0; kt < NK; ++kt) {
    const int c = kt & 1, nb = c ^ 1;
    const bool more = kt + 1 < NK;
    bf16x8 a0[MQ][2], a1[MQ][2], b0[2][2], b1[2][2];

    // ---- phase 0: issue ALL next-tile loads; read A-half0 + B-half0 ----
    if (more) stageAll(nb, kt + 1);
#pragma unroll
    for (int mi = 0; mi < MQ; ++mi)
#pragma unroll
      for (int ks = 0; ks < 2; ++ks) a0[mi][ks] = rdA(c, wr * WM + mi * 16 + lr, ks);
#pragma unroll
    for (int ni = 0; ni < 2; ++ni)
#pragma unroll
      for (int ks = 0; ks < 2; ++ks) b0[ni][ks] = rdB(c, wc * 64 + ni * 16 + lr, ks);
    BAR();
    WAIT_LGKM0;
    __builtin_amdgcn_s_setprio(1);
#pragma unroll
    for (int mi = 0; mi < MQ; ++mi)
#pragma unroll
      for (int ni = 0; ni < 2; ++ni)
#pragma unroll
        for (int ks = 0; ks < 2; ++ks)
          acc[mi][ni] = __builtin_amdgcn_mfma_f32_16x16x32_bf16(a0[mi][ks], b0[ni][ks], acc[mi][ni], 0, 0, 0);
    __builtin_amdgcn_s_setprio(0);
    BAR();

    // ---- phase 1: read B-half1 ----
#pragma unroll
    for (int ni = 0; ni < 2; ++ni)
#pragma unroll
      for (int ks = 0; ks < 2; ++ks) b1[ni][ks] = rdB(c, wc * 64 + (2 + ni) * 16 + lr, ks);
    BAR();
    WAIT_LGKM0;
    __builtin_amdgcn_s_setprio(1);
#pragma unroll
    for (int mi = 0; mi < MQ; ++mi)
#pragma unroll
      for (int ni = 0; ni < 2; ++ni)
#pragma unroll
        for (int ks = 0; ks < 2; ++ks)
          acc[mi][2 + ni] = __builtin_amdgcn_mfma_f32_16x16x32_bf16(a0[mi][ks], b1[ni][ks], acc[mi][2 + ni], 0, 0, 0);
    __builtin_amdgcn_s_setprio(0);
    BAR();

    // ---- phase 2: read A-half1 ----
#pragma unroll
    for (int mi = 0; mi < MQ; ++mi)
#pragma unroll
      for (int ks = 0; ks < 2; ++ks) a1[mi][ks] = rdA(c, wr * WM + (MQ + mi) * 16 + lr, ks);
    BAR();
    WAIT_LGKM0;
    __builtin_amdgcn_s_setprio(1);
#pragma unroll
    for (int mi = 0; mi < MQ; ++mi)
#pragma unroll
      for (int ni = 0; ni < 2; ++ni)
#pragma unroll
        for (int ks = 0; ks < 2; ++ks)
          acc[MQ + mi][ni] = __builtin_amdgcn_mfma_f32_16x16x32_bf16(a1[mi][ks], b0[ni][ks], acc[MQ + mi][ni], 0, 0, 0);
    __builtin_amdgcn_s_setprio(0);
    BAR();

    // ---- phase 3: pure MFMA; then wait the (covered) prefetch, tile boundary ----
    __builtin_amdgcn_s_setprio(1);
#pragma unroll
    for (int mi = 0; mi < MQ; ++mi)
#pragma unroll
      for (int ni = 0; ni < 2; ++ni)
#pragma unroll
        for (int ks = 0; ks < 2; ++ks)
          acc[MQ + mi][2 + ni] = __builtin_amdgcn_mfma_f32_16x16x32_bf16(a1[mi][ks], b1[ni][ks], acc[MQ + mi][2 + ni], 0, 0, 0);
    __builtin_amdgcn_s_setprio(0);
    WAIT_VM0;
    BAR();
  }

  // ---- epilogue ----
  const int row0 = bm * BM + wr * WM;
  const int col0 = bn * BN + wc * 64;
#pragma unroll
  for (int m = 0; m < MI; ++m) {
#pragma unroll
    for (int n = 0; n < 4; ++n) {
      const int col = col0 + n * 16 + lr;
      float bc = 0.0f;
      if (E & EP_BIAS) bc = bias[col];
#pragma unroll
      for (int j = 0; j < 4; ++j) {
        const int row = row0 + m * 16 + lg * 4 + j;
        float v = acc[m][n][j] + bc;
        if (E & EP_RES) v += resid[(size_t)row * N + col];
        if (E & EP_GELU) v = gelu_f(v);
        if (E & EP_QSCALE) { if (col < 1024) v *= 0.18033688011112042f; }  // 0.125*log2(e)
        if (E & EP_BF16) ((unsigned short*)out)[(size_t)row * N + col] = f2bf(v);
        else ((float*)out)[(size_t)row * N + col] = v;
      }
    }
  }
}

// ---------------- Flash attention: causal, 16 heads, Dh=64, KVBLK=128 ----------------
// S^T = mfma(K,Q): lane owns one q-row's 128-k strip (log2 domain; Q pre-scaled by
// 0.125*log2e). Lane-local softmax + defer-max (THR=8). In-register P->B-frag via
// cvt_pk + permlane swaps. O^T = mfma(V^T, P^T). Blocks pair (qt, 15-qt): 17 iters each.
__global__ __launch_bounds__(512, 4) void attn_k(const unsigned short* __restrict__ qkv,
                                                 unsigned short* __restrict__ out) {
  __shared__ __align__(16) unsigned short Kl[2][128 * 64];  // [128 s][128B], swizzled
  __shared__ __align__(16) unsigned short Vt[2][64 * 128];  // [64 dh][256B], swizzled
  const int tid = threadIdx.x;
  const int l = tid & 63, w = tid >> 6;
  const int lr = l & 15, lg = l >> 4;
  const int bh = blockIdx.y;
  const int b = bh >> 4, h = bh & 15;
  const size_t rowbase = (size_t)b * SEQ;
  char* klb = (char*)Kl;
  char* vtb = (char*)Vt;

  const int srow8 = l >> 3;
  const int kslot = (l & 7) ^ (srow8 & 7);
  auto stageK = [&](int buf, int kb2) {
#pragma unroll
    for (int s = w; s < 16; s += 8) {
      const char* src = (const char*)(qkv + (rowbase + kb2 + s * 8 + srow8) * QLD + 1024 + h * 64)
                        + kslot * 16;
      gl16(src, klb + buf * 16384 + s * 1024 + l * 16);
    }
  };
  const int sg = tid & 31, dhg = tid >> 5;  // 32 s-groups x 16 dh-groups
  auto loadV = [&](int kb2, uint2* vr) {
#pragma unroll
    for (int i = 0; i < 4; ++i)
      vr[i] = *reinterpret_cast<const uint2*>(
          qkv + (rowbase + kb2 + sg * 4 + i) * QLD + 2048 + h * 64 + dhg * 4);
  };
  auto writeV = [&](int buf, const uint2* vr) {
    char* vb = vtb + buf * 16384;
#pragma unroll
    for (int jj = 0; jj < 4; ++jj) {
      const int dh = dhg * 4 + jj;
      unsigned a0 = (jj < 2) ? vr[0].x : vr[0].y;
      unsigned a1 = (jj < 2) ? vr[1].x : vr[1].y;
      unsigned a2 = (jj < 2) ? vr[2].x : vr[2].y;
      unsigned a3 = (jj < 2) ? vr[3].x : vr[3].y;
      unsigned s01, s23;
      if (jj & 1) {
        s01 = (a0 >> 16) | (a1 & 0xffff0000u);
        s23 = (a2 >> 16) | (a3 & 0xffff0000u);
      } else {
        s01 = (a0 & 0xffffu) | (a1 << 16);
        s23 = (a2 & 0xffffu) | (a3 << 16);
      }
      const int bo = dh * 256 + (((sg >> 1) ^ (dh & 15)) << 4) + ((sg & 1) << 3);
      uint2 p; p.x = s01; p.y = s23;
      *reinterpret_cast<uint2*>(vb + bo) = p;
    }
  };

#pragma unroll 1
  for (int seg = 0; seg < 2; ++seg) {
    const int qt = seg ? (15 - blockIdx.x) : blockIdx.x;
    const int q0 = qt << 7;
    const int qwmin = q0 + w * 16;
    const int qrow = qwmin + lr;

    bf16x8 qf[2];
#pragma unroll
    for (int ks = 0; ks < 2; ++ks)
      qf[ks] = *reinterpret_cast<const bf16x8*>(
          qkv + (rowbase + qrow) * QLD + h * 64 + ks * 32 + lg * 8);

    f32x4 oacc[4];
#pragma unroll
    for (int n = 0; n < 4; ++n) oacc[n] = 0.0f;
    float mrun = -1e30f, lrun = 0.0f;

    {
      stageK(0, 0);
      uint2 vr0[4];
      loadV(0, vr0);
      writeV(0, vr0);
    }
    __syncthreads();

#pragma unroll 1
    for (int kt = 0; kt <= qt; ++kt) {
      const int cur = kt & 1, nb = cur ^ 1;
      const int kb = kt << 7;
      const bool more = kt < qt;
      uint2 vr[4];
      if (more) { stageK(nb, kb + 128); loadV(kb + 128, vr); }

      // ---- S^T = K * Q^T : 8 k-rows x 2 dh-chunks ----
      f32x4 sacc[8];
#pragma unroll
      for (int ni = 0; ni < 8; ++ni) sacc[ni] = 0.0f;
      const char* kc = klb + cur * 16384;
      __builtin_amdgcn_s_setprio(1);
#pragma unroll
      for (int ks = 0; ks < 2; ++ks) {
#pragma unroll
        for (int ni = 0; ni < 8; ++ni) {
          const int r = ni * 16 + lr;
          const int bo = r * 128 + ((((ks << 2) + lg) ^ (r & 7)) << 4);
          bf16x8 kf = *reinterpret_cast<const bf16x8*>(kc + bo);
          sacc[ni] = __builtin_amdgcn_mfma_f32_16x16x32_bf16(kf, qf[ks], sacc[ni], 0, 0, 0);
        }
      }
      __builtin_amdgcn_s_setprio(0);

      // ---- causal mask (diag tile only; scores already in log2 domain) ----
      if (kt == qt) {
#pragma unroll
        for (int ni = 0; ni < 8; ++ni)
#pragma unroll
          for (int j = 0; j < 4; ++j)
            if (kb + ni * 16 + lg * 4 + j > qrow) sacc[ni][j] = -1e30f;
      }

      // ---- online softmax (lane-local, 2 shuffles, defer-max THR=8) ----
      float pm = sacc[0][0];
#pragma unroll
      for (int ni = 0; ni < 8; ++ni)
#pragma unroll
        for (int j = 0; j < 4; ++j) pm = fmaxf(pm, sacc[ni][j]);
      pm = fmaxf(pm, __shfl_xor(pm, 16, 64));
      pm = fmaxf(pm, __shfl_xor(pm, 32, 64));
      if (!__all(pm <= mrun + 8.0f)) {
        const float mnew = fmaxf(mrun, pm);
        const float alpha = exp2f(mrun - mnew);
        mrun = mnew;
        lrun *= alpha;
#pragma unroll
        for (int n = 0; n < 4; ++n) oacc[n] *= alpha;
      }
      float rs = 0.0f;
#pragma unroll
      for (int ni = 0; ni < 8; ++ni)
#pragma unroll
        for (int j = 0; j < 4; ++j) {
          const float p = exp2f(sacc[ni][j] - mrun);
          sacc[ni][j] = p;
          rs += p;
        }
      rs += __shfl_xor(rs, 16, 64);
      rs += __shfl_xor(rs, 32, 64);
      lrun += rs;

      if (more) writeV(nb, vr);  // HBM latency hid under QK + softmax

      // ---- O^T += V^T * P^T : 4 k-chunks of 32 ----
      const char* vc = vtb + cur * 16384;
#pragma unroll
      for (int g = 0; g < 4; ++g) {
        unsigned U0, U1, U2, U3, C0, C1, W0, W1, W2, W3;
        CVTPK(U0, sacc[2 * g][0], sacc[2 * g][1]);
        CVTPK(U1, sacc[2 * g][2], sacc[2 * g][3]);
        CVTPK(U2, sacc[2 * g + 1][0], sacc[2 * g + 1][1]);
        CVTPK(U3, sacc[2 * g + 1][2], sacc[2 * g + 1][3]);
        P32SWAP(U0, U2, C0, C1);
        P16SWAP(C0, C1, W0, W2);
        P32SWAP(U1, U3, C0, C1);
        P16SWAP(C0, C1, W1, W3);
        union { uint4 u; bf16x8 v; } pu;
        pu.u = make_uint4(W0, W1, W2, W3);
        __builtin_amdgcn_s_setprio(1);
#pragma unroll
        for (int n = 0; n < 4; ++n) {
          const int r = n * 16 + lr;
          const int bo = r * 256 + ((((g << 2) + lg) ^ (r & 15)) << 4);
          bf16x8 vf = *reinterpret_cast<const bf16x8*>(vc + bo);
          oacc[n] = __builtin_amdgcn_mfma_f32_16x16x32_bf16(vf, pu.v, oacc[n], 0, 0, 0);
        }
        __builtin_amdgcn_s_setprio(0);
      }
      __syncthreads();
    }

    // ---- finalize: lane holds q=qrow, dh = n*16 + lg*4 + j ----
    const float inv = 1.0f / lrun;
#pragma unroll
    for (int n = 0; n < 4; ++n) {
      ushort4 o;
      o.x = f2bf(oacc[n][0] * inv);
      o.y = f2bf(oacc[n][1] * inv);
      o.z = f2bf(oacc[n][2] * inv);
      o.w = f2bf(oacc[n][3] * inv);
      *reinterpret_cast<ushort4*>(out + (rowbase + qrow) * 1024 + h * 64 + n * 16 + lg * 4) = o;
    }
  }
}

// ---------------- host ----------------
extern "C" void kernel_launch(void* const* d_in, const int* in_sizes, int n_in,
                              void* d_out, int out_size, void* d_ws, size_t ws_size,
                              hipStream_t stream) {
  const float* x   = (const float*)d_in[0];
  const float* Wq  = (const float*)d_in[1];
  const float* bq  = (const float*)d_in[2];
  const float* Wk  = (const float*)d_in[3];
  const float* bk  = (const float*)d_in[4];
  const float* Wv  = (const float*)d_in[5];
  const float* bv  = (const float*)d_in[6];
  const float* Wo  = (const float*)d_in[7];
  const float* W1  = (const float*)d_in[8];
  const float* b1  = (const float*)d_in[9];
  const float* W2  = (const float*)d_in[10];
  const float* b2  = (const float*)d_in[11];
  const float* g1  = (const float*)d_in[12];
  const float* be1 = (const float*)d_in[13];
  const float* g2  = (const float*)d_in[14];
  const float* be2 = (const float*)d_in[15];

  char* ws = (char*)d_ws;
  size_t off = 0;
  auto alloc = [&](size_t bytes) { char* p = ws + off; off += (bytes + 255) & ~(size_t)255; return p; };
  unsigned short* WqkvT = (unsigned short*)alloc((size_t)3072 * 1024 * 2);
  unsigned short* WoT   = (unsigned short*)alloc((size_t)1024 * 1024 * 2);
  unsigned short* W1T   = (unsigned short*)alloc((size_t)4096 * 1024 * 2);
  unsigned short* W2T   = (unsigned short*)alloc((size_t)1024 * 4096 * 2);
  float*          bqkv  = (float*)alloc((size_t)3072 * 4);
  unsigned short* normed = (unsigned short*)alloc((size_t)NROWS * 1024 * 2);
  unsigned short* qkvbuf = (unsigned short*)alloc((size_t)NROWS * 4096 * 2);
  unsigned short* attnb  = (unsigned short*)alloc((size_t)NROWS * 1024 * 2);
  float*          x1     = (float*)alloc((size_t)NROWS * 1024 * 4);

  const dim3 tb(32, 8);
  transpose_cvt<<<dim3(32, 32), tb, 0, stream>>>(Wq, WqkvT, 1024, 1024);
  transpose_cvt<<<dim3(32, 32), tb, 0, stream>>>(Wk, WqkvT + 1024 * 1024, 1024, 1024);
  transpose_cvt<<<dim3(32, 32), tb, 0, stream>>>(Wv, WqkvT + 2 * 1024 * 1024, 1024, 1024);
  transpose_cvt<<<dim3(32, 32), tb, 0, stream>>>(Wo, WoT, 1024, 1024);
  transpose_cvt<<<dim3(128, 32), tb, 0, stream>>>(W1, W1T, 1024, 4096);
  transpose_cvt<<<dim3(32, 128), tb, 0, stream>>>(W2, W2T, 4096, 1024);
  concat_bias<<<12, 256, 0, stream>>>(bq, bk, bv, bqkv);

  layernorm_k<<<NROWS, 256, 0, stream>>>(x, g1, be1, normed);
  gemm8_k<256, (EP_BIAS | EP_BF16 | EP_QSCALE)><<<dim3(12, 32), 512, 0, stream>>>(normed, WqkvT, bqkv, nullptr, qkvbuf, NROWS, 3072, 1024);
  attn_k<<<dim3(8, 64), 512, 0, stream>>>(qkvbuf, attnb);
  gemm8_k<128, EP_RES><<<dim3(4, 64), 512, 0, stream>>>(attnb, WoT, nullptr, x, x1, NROWS, 1024, 1024);
  layernorm_k<<<NROWS, 256, 0, stream>>>(x1, g2, be2, normed);
  gemm8_k<256, (EP_BIAS | EP_GELU | EP_BF16)><<<dim3(16, 32), 512, 0, stream>>>(normed, W1T, b1, nullptr, qkvbuf, NROWS, 4096, 1024);
  gemm8_k<128, (EP_BIAS | EP_RES)><<<dim3(4, 64), 512, 0, stream>>>(qkvbuf, W2T, b2, x1, d_out, NROWS, 1024, 4096);
}

// Round 5
// 542.198 us; speedup vs baseline: 1.0992x; 1.0992x over previous
//
#include <hip/hip_runtime.h>

#define SEQ 2048
#define NROWS 8192            // 4 * 2048
#define NH 16
#define DHEAD 64
#define QLD 3072              // q,k,v concatenated columns

typedef float f32x4 __attribute__((ext_vector_type(4)));
typedef __bf16 bf16x8 __attribute__((ext_vector_type(8)));

__device__ __forceinline__ unsigned short f2bf(float f) {
  union { float f; unsigned u; } v; v.f = f;
  unsigned r = v.u + 0x7fffu + ((v.u >> 16) & 1u);
  return (unsigned short)(r >> 16);
}

__device__ __forceinline__ void gl16(const void* g, void* l) {
  __builtin_amdgcn_global_load_lds((const __attribute__((address_space(1))) void*)g,
                                   (__attribute__((address_space(3))) void*)l, 16, 0, 0);
}

__device__ __forceinline__ float gelu_f(float x) {
  float t = 0.7978845608028654f * (x + 0.044715f * x * x * x);
  float e = __expf(2.0f * t);
  float th = 1.0f - 2.0f / (e + 1.0f);   // tanh(t), saturates cleanly
  return 0.5f * x * (1.0f + th);
}

#define CVTPK(dst, lo, hi) asm("v_cvt_pk_bf16_f32 %0, %1, %2" : "=v"(dst) : "v"(lo), "v"(hi))

#if __has_builtin(__builtin_amdgcn_permlane32_swap)
#define P32SWAP(a, b, x, y) { auto _t = __builtin_amdgcn_permlane32_swap((a), (b), false, false); (x) = _t[0]; (y) = _t[1]; }
#else
#define P32SWAP(a, b, x, y) { unsigned _as = (unsigned)__shfl_xor((int)(a), 32, 64); \
  unsigned _bs = (unsigned)__shfl_xor((int)(b), 32, 64); \
  (x) = (l < 32) ? (a) : _bs; (y) = (l < 32) ? _as : (b); }
#endif
#if __has_builtin(__builtin_amdgcn_permlane16_swap)
#define P16SWAP(a, b, x, y) { auto _t = __builtin_amdgcn_permlane16_swap((a), (b), false, false); (x) = _t[0]; (y) = _t[1]; }
#else
#define P16SWAP(a, b, x, y) { unsigned _as = (unsigned)__shfl_xor((int)(a), 16, 64); \
  unsigned _bs = (unsigned)__shfl_xor((int)(b), 16, 64); \
  (x) = (l & 16) ? _bs : (a); (y) = (l & 16) ? (b) : _as; }
#endif

#define MEMFENCE asm volatile("" ::: "memory")
#define BAR() do { MEMFENCE; __builtin_amdgcn_s_barrier(); MEMFENCE; } while (0)
#define WAIT_LGKM0 asm volatile("s_waitcnt lgkmcnt(0)" ::: "memory")
#define WAIT_VM6 asm volatile("s_waitcnt vmcnt(6)" ::: "memory")
#define WAIT_VM0 asm volatile("s_waitcnt vmcnt(0)" ::: "memory")

// ---------------- transpose + fp32->bf16 convert: Wt[n][k] = W[k][n] ----------------
__global__ __launch_bounds__(256) void transpose_cvt(const float* __restrict__ W,
                                                     unsigned short* __restrict__ Wt,
                                                     int K, int N) {
  __shared__ float tile[32][33];
  const int tx = threadIdx.x, ty = threadIdx.y;
  const int n0 = blockIdx.x * 32, k0 = blockIdx.y * 32;
#pragma unroll
  for (int i = ty; i < 32; i += 8)
    tile[i][tx] = W[(size_t)(k0 + i) * N + n0 + tx];
  __syncthreads();
#pragma unroll
  for (int i = ty; i < 32; i += 8)
    Wt[(size_t)(n0 + i) * K + k0 + tx] = f2bf(tile[tx][i]);
}

__global__ __launch_bounds__(256) void concat_bias(const float* __restrict__ bq,
                                                   const float* __restrict__ bk,
                                                   const float* __restrict__ bv,
                                                   float* __restrict__ dst) {
  int i = blockIdx.x * 256 + threadIdx.x;
  if (i < 1024) dst[i] = bq[i];
  else if (i < 2048) dst[i] = bk[i - 1024];
  else if (i < 3072) dst[i] = bv[i - 2048];
}

// ---------------- LayerNorm: fp32 in -> bf16 out, one block per 1024-row ----------------
__global__ __launch_bounds__(256) void layernorm_k(const float* __restrict__ x,
                                                   const float* __restrict__ g,
                                                   const float* __restrict__ b,
                                                   unsigned short* __restrict__ out) {
  const int row = blockIdx.x, tid = threadIdx.x;
  const float4 v = reinterpret_cast<const float4*>(x + (size_t)row * 1024)[tid];
  float s = v.x + v.y + v.z + v.w;
  float s2 = v.x * v.x + v.y * v.y + v.z * v.z + v.w * v.w;
#pragma unroll
  for (int d = 1; d < 64; d <<= 1) { s += __shfl_xor(s, d, 64); s2 += __shfl_xor(s2, d, 64); }
  __shared__ float ls[4], ls2[4];
  const int w = tid >> 6;
  if ((tid & 63) == 0) { ls[w] = s; ls2[w] = s2; }
  __syncthreads();
  s = ls[0] + ls[1] + ls[2] + ls[3];
  s2 = ls2[0] + ls2[1] + ls2[2] + ls2[3];
  const float mu = s * (1.0f / 1024.0f);
  const float var = s2 * (1.0f / 1024.0f) - mu * mu;
  const float rstd = rsqrtf(var + 1e-6f);
  const float4 gv = reinterpret_cast<const float4*>(g)[tid];
  const float4 bv = reinterpret_cast<const float4*>(b)[tid];
  ushort4 o;
  o.x = f2bf((v.x - mu) * rstd * gv.x + bv.x);
  o.y = f2bf((v.y - mu) * rstd * gv.y + bv.y);
  o.z = f2bf((v.z - mu) * rstd * gv.z + bv.z);
  o.w = f2bf((v.w - mu) * rstd * gv.w + bv.w);
  reinterpret_cast<ushort4*>(out + (size_t)row * 1024)[tid] = o;
}

enum { EP_BIAS = 1, EP_RES = 2, EP_GELU = 4, EP_BF16 = 8, EP_QSCALE = 16 };

// ---------------- 3-slot ring GEMM: C[M,N] = A[M,K] * Bt[N,K]^T + epilogue ----------
// BM=256, BN=128, BK=64, 512 threads (8 waves, 4M x 2N, wave-tile 64x64).
// LDS = 3 slots x (A 32KB + B 16KB) = 144KB (1 block/CU). Per tile:
// vmcnt(6) [tile t's loads landed; only tile t+1's 6 are younger] -> barrier ->
// issue tile t+2's 6 global_load_lds -> 16 swizzled ds_read_b128 + 32 MFMA ->
// lgkmcnt(0). No vmcnt(0) drain in the main loop (T4); XOR-swizzle (T2);
// setprio (T5); XCD-chunked block order (T1).
template <int E>
__global__ __launch_bounds__(512) void gemm3_k(const unsigned short* __restrict__ A,
                                               const unsigned short* __restrict__ Bt,
                                               const float* __restrict__ bias,
                                               const float* __restrict__ resid,
                                               void* __restrict__ out,
                                               int M, int N, int K) {
  __shared__ __align__(16) unsigned short Ls[3][24576];  // per slot: A[0..16383] B[16384..24575]
  const int tid = threadIdx.x;
  const int l = tid & 63, w = tid >> 6;
  const int lr = l & 15, lg = l >> 4;
  const int wr = w >> 1, wc = w & 1;

  // T1: bijective XCD chunking (nwg % 8 == 0 for all grids); within a chunk,
  // consecutive lin share bm (A-panel L2 reuse).
  const int gx = gridDim.x;
  const int nwg = gx * gridDim.y;
  int lin = blockIdx.y * gx + blockIdx.x;
  lin = (lin & 7) * (nwg >> 3) + (lin >> 3);
  const int bn = lin % gx, bm = lin / gx;

  const unsigned short* Ab = A + (size_t)(bm * 256) * K;
  const unsigned short* Bb = Bt + (size_t)(bn * 128) * K;
  const int NK = K >> 6;

  const int srow8 = l >> 3;                 // 0..7
  const int sslot = (l & 7) ^ srow8;        // inverse-swizzled source slot
  const size_t rs8 = (size_t)8 * K * 2;     // 8-row stride in bytes

  auto stage = [&](int slot, int t) {
    if (t >= NK) return;
    char* base = (char*)(&Ls[slot][0]);
    const char* a0 = (const char*)(Ab + (size_t)srow8 * K + t * 64) + sslot * 16;
    const char* b0 = (const char*)(Bb + (size_t)srow8 * K + t * 64) + sslot * 16;
    gl16(a0 + (size_t)w * rs8,        base + w * 1024 + l * 16);
    gl16(a0 + (size_t)(8 + w) * rs8,  base + (8 + w) * 1024 + l * 16);
    gl16(a0 + (size_t)(16 + w) * rs8, base + (16 + w) * 1024 + l * 16);
    gl16(a0 + (size_t)(24 + w) * rs8, base + (24 + w) * 1024 + l * 16);
    gl16(b0 + (size_t)w * rs8,        base + 32768 + w * 1024 + l * 16);
    gl16(b0 + (size_t)(8 + w) * rs8,  base + 32768 + (8 + w) * 1024 + l * 16);
  };
  auto rd = [&](const char* base, int r, int ks) {
    return *reinterpret_cast<const bf16x8*>(base + r * 128 + (((ks << 2) + lg) ^ (r & 7)) * 16);
  };

  f32x4 acc[4][4];
#pragma unroll
  for (int m = 0; m < 4; ++m)
#pragma unroll
    for (int n = 0; n < 4; ++n) acc[m][n] = 0.0f;

  stage(0, 0);
  stage(1, 1);
  int cs = 0, ss = 2;

  for (int t = 0; t < NK; ++t) {
    if (t + 1 < NK) { WAIT_VM6; } else { WAIT_VM0; }
    BAR();
    stage(ss, t + 2);

    const char* Ac = (const char*)(&Ls[cs][0]);
    const char* Bc = Ac + 32768;
    bf16x8 af[4][2], bf[4][2];
#pragma unroll
    for (int mi = 0; mi < 4; ++mi)
#pragma unroll
      for (int ks = 0; ks < 2; ++ks) af[mi][ks] = rd(Ac, wr * 64 + mi * 16 + lr, ks);
#pragma unroll
    for (int ni = 0; ni < 4; ++ni)
#pragma unroll
      for (int ks = 0; ks < 2; ++ks) bf[ni][ks] = rd(Bc, wc * 64 + ni * 16 + lr, ks);

    __builtin_amdgcn_s_setprio(1);
#pragma unroll
    for (int mi = 0; mi < 4; ++mi)
#pragma unroll
      for (int ni = 0; ni < 4; ++ni)
#pragma unroll
        for (int ks = 0; ks < 2; ++ks)
          acc[mi][ni] = __builtin_amdgcn_mfma_f32_16x16x32_bf16(af[mi][ks], bf[ni][ks], acc[mi][ni], 0, 0, 0);
    __builtin_amdgcn_s_setprio(0);
    WAIT_LGKM0;  // LDS pipe drained before next tile's barrier (cross-wave WAR)

    cs = (cs == 2) ? 0 : cs + 1;
    ss = (ss == 2) ? 0 : ss + 1;
  }

  // ---- epilogue ----
  const int row0 = bm * 256 + wr * 64;
  const int col0 = bn * 128 + wc * 64;
#pragma unroll
  for (int m = 0; m < 4; ++m) {
#pragma unroll
    for (int n = 0; n < 4; ++n) {
      const int col = col0 + n * 16 + lr;
      float bc = 0.0f;
      if (E & EP_BIAS) bc = bias[col];
#pragma unroll
      for (int j = 0; j < 4; ++j) {
        const int row = row0 + m * 16 + lg * 4 + j;
        float v = acc[m][n][j] + bc;
        if (E & EP_RES) v += resid[(size_t)row * N + col];
        if (E & EP_GELU) v = gelu_f(v);
        if (E & EP_QSCALE) { if (col < 1024) v *= 0.18033688011112042f; }  // 0.125*log2(e)
        if (E & EP_BF16) ((unsigned short*)out)[(size_t)row * N + col] = f2bf(v);
        else ((float*)out)[(size_t)row * N + col] = v;
      }
    }
  }
}

// ---------------- Flash attention: causal, 16 heads, Dh=64, KVBLK=128 ----------------
// S^T = mfma(K,Q): lane owns one q-row's 128-k strip (log2 domain; Q pre-scaled by
// 0.125*log2e). Lane-local softmax + defer-max (THR=8). In-register P->B-frag via
// cvt_pk + permlane swaps. O^T = mfma(V^T, P^T). Blocks pair (qt, 15-qt).
// launch_bounds(512,2): R4's (512,4) capped VGPR at 64 -> scratch spill (+28MB traffic).
__global__ __launch_bounds__(512, 2) void attn_k(const unsigned short* __restrict__ qkv,
                                                 unsigned short* __restrict__ out) {
  __shared__ __align__(16) unsigned short Kl[2][128 * 64];  // [128 s][128B], swizzled
  __shared__ __align__(16) unsigned short Vt[2][64 * 128];  // [64 dh][256B], swizzled
  const int tid = threadIdx.x;
  const int l = tid & 63, w = tid >> 6;
  const int lr = l & 15, lg = l >> 4;
  const int bh = blockIdx.y;
  const int b = bh >> 4, h = bh & 15;
  const size_t rowbase = (size_t)b * SEQ;
  char* klb = (char*)Kl;
  char* vtb = (char*)Vt;

  const int srow8 = l >> 3;
  const int kslot = (l & 7) ^ (srow8 & 7);
  auto stageK = [&](int buf, int kb2) {
#pragma unroll
    for (int s = w; s < 16; s += 8) {
      const char* src = (const char*)(qkv + (rowbase + kb2 + s * 8 + srow8) * QLD + 1024 + h * 64)
                        + kslot * 16;
      gl16(src, klb + buf * 16384 + s * 1024 + l * 16);
    }
  };
  const int sg = tid & 31, dhg = tid >> 5;  // 32 s-groups x 16 dh-groups
  auto loadV = [&](int kb2, uint2* vr) {
#pragma unroll
    for (int i = 0; i < 4; ++i)
      vr[i] = *reinterpret_cast<const uint2*>(
          qkv + (rowbase + kb2 + sg * 4 + i) * QLD + 2048 + h * 64 + dhg * 4);
  };
  auto writeV = [&](int buf, const uint2* vr) {
    char* vb = vtb + buf * 16384;
#pragma unroll
    for (int jj = 0; jj < 4; ++jj) {
      const int dh = dhg * 4 + jj;
      unsigned a0 = (jj < 2) ? vr[0].x : vr[0].y;
      unsigned a1 = (jj < 2) ? vr[1].x : vr[1].y;
      unsigned a2 = (jj < 2) ? vr[2].x : vr[2].y;
      unsigned a3 = (jj < 2) ? vr[3].x : vr[3].y;
      unsigned s01, s23;
      if (jj & 1) {
        s01 = (a0 >> 16) | (a1 & 0xffff0000u);
        s23 = (a2 >> 16) | (a3 & 0xffff0000u);
      } else {
        s01 = (a0 & 0xffffu) | (a1 << 16);
        s23 = (a2 & 0xffffu) | (a3 << 16);
      }
      const int bo = dh * 256 + (((sg >> 1) ^ (dh & 15)) << 4) + ((sg & 1) << 3);
      uint2 p; p.x = s01; p.y = s23;
      *reinterpret_cast<uint2*>(vb + bo) = p;
    }
  };

#pragma unroll 1
  for (int seg = 0; seg < 2; ++seg) {
    const int qt = seg ? (15 - blockIdx.x) : blockIdx.x;
    const int q0 = qt << 7;
    const int qwmin = q0 + w * 16;
    const int qrow = qwmin + lr;

    bf16x8 qf[2];
#pragma unroll
    for (int ks = 0; ks < 2; ++ks)
      qf[ks] = *reinterpret_cast<const bf16x8*>(
          qkv + (rowbase + qrow) * QLD + h * 64 + ks * 32 + lg * 8);

    f32x4 oacc[4];
#pragma unroll
    for (int n = 0; n < 4; ++n) oacc[n] = 0.0f;
    float mrun = -1e30f, lrun = 0.0f;

    {
      stageK(0, 0);
      uint2 vr0[4];
      loadV(0, vr0);
      writeV(0, vr0);
    }
    __syncthreads();

#pragma unroll 1
    for (int kt = 0; kt <= qt; ++kt) {
      const int cur = kt & 1, nb = cur ^ 1;
      const int kb = kt << 7;
      const bool more = kt < qt;
      uint2 vr[4];
      if (more) { stageK(nb, kb + 128); loadV(kb + 128, vr); }

      // ---- S^T = K * Q^T : 8 k-rows x 2 dh-chunks ----
      f32x4 sacc[8];
#pragma unroll
      for (int ni = 0; ni < 8; ++ni) sacc[ni] = 0.0f;
      const char* kc = klb + cur * 16384;
      __builtin_amdgcn_s_setprio(1);
#pragma unroll
      for (int ks = 0; ks < 2; ++ks) {
#pragma unroll
        for (int ni = 0; ni < 8; ++ni) {
          const int r = ni * 16 + lr;
          const int bo = r * 128 + ((((ks << 2) + lg) ^ (r & 7)) << 4);
          bf16x8 kf = *reinterpret_cast<const bf16x8*>(kc + bo);
          sacc[ni] = __builtin_amdgcn_mfma_f32_16x16x32_bf16(kf, qf[ks], sacc[ni], 0, 0, 0);
        }
      }
      __builtin_amdgcn_s_setprio(0);

      // ---- causal mask (diag tile only; scores in log2 domain) ----
      if (kt == qt) {
#pragma unroll
        for (int ni = 0; ni < 8; ++ni)
#pragma unroll
          for (int j = 0; j < 4; ++j)
            if (kb + ni * 16 + lg * 4 + j > qrow) sacc[ni][j] = -1e30f;
      }

      // ---- online softmax (lane-local, 2 shuffles, defer-max THR=8) ----
      float pm = sacc[0][0];
#pragma unroll
      for (int ni = 0; ni < 8; ++ni)
#pragma unroll
        for (int j = 0; j < 4; ++j) pm = fmaxf(pm, sacc[ni][j]);
      pm = fmaxf(pm, __shfl_xor(pm, 16, 64));
      pm = fmaxf(pm, __shfl_xor(pm, 32, 64));
      if (!__all(pm <= mrun + 8.0f)) {
        const float mnew = fmaxf(mrun, pm);
        const float alpha = exp2f(mrun - mnew);
        mrun = mnew;
        lrun *= alpha;
#pragma unroll
        for (int n = 0; n < 4; ++n) oacc[n] *= alpha;
      }
      float rs = 0.0f;
#pragma unroll
      for (int ni = 0; ni < 8; ++ni)
#pragma unroll
        for (int j = 0; j < 4; ++j) {
          const float p = exp2f(sacc[ni][j] - mrun);
          sacc[ni][j] = p;
          rs += p;
        }
      rs += __shfl_xor(rs, 16, 64);
      rs += __shfl_xor(rs, 32, 64);
      lrun += rs;

      if (more) writeV(nb, vr);  // HBM latency hid under QK + softmax

      // ---- O^T += V^T * P^T : 4 k-chunks of 32 ----
      const char* vc = vtb + cur * 16384;
#pragma unroll
      for (int g = 0; g < 4; ++g) {
        unsigned U0, U1, U2, U3, C0, C1, W0, W1, W2, W3;
        CVTPK(U0, sacc[2 * g][0], sacc[2 * g][1]);
        CVTPK(U1, sacc[2 * g][2], sacc[2 * g][3]);
        CVTPK(U2, sacc[2 * g + 1][0], sacc[2 * g + 1][1]);
        CVTPK(U3, sacc[2 * g + 1][2], sacc[2 * g + 1][3]);
        P32SWAP(U0, U2, C0, C1);
        P16SWAP(C0, C1, W0, W2);
        P32SWAP(U1, U3, C0, C1);
        P16SWAP(C0, C1, W1, W3);
        union { uint4 u; bf16x8 v; } pu;
        pu.u = make_uint4(W0, W1, W2, W3);
        __builtin_amdgcn_s_setprio(1);
#pragma unroll
        for (int n = 0; n < 4; ++n) {
          const int r = n * 16 + lr;
          const int bo = r * 256 + ((((g << 2) + lg) ^ (r & 15)) << 4);
          bf16x8 vf = *reinterpret_cast<const bf16x8*>(vc + bo);
          oacc[n] = __builtin_amdgcn_mfma_f32_16x16x32_bf16(vf, pu.v, oacc[n], 0, 0, 0);
        }
        __builtin_amdgcn_s_setprio(0);
      }
      __syncthreads();
    }

    // ---- finalize ----
    const float inv = 1.0f / lrun;
#pragma unroll
    for (int n = 0; n < 4; ++n) {
      ushort4 o;
      o.x = f2bf(oacc[n][0] * inv);
      o.y = f2bf(oacc[n][1] * inv);
      o.z = f2bf(oacc[n][2] * inv);
      o.w = f2bf(oacc[n][3] * inv);
      *reinterpret_cast<ushort4*>(out + (rowbase + qrow) * 1024 + h * 64 + n * 16 + lg * 4) = o;
    }
  }
}

// ---------------- host ----------------
extern "C" void kernel_launch(void* const* d_in, const int* in_sizes, int n_in,
                              void* d_out, int out_size, void* d_ws, size_t ws_size,
                              hipStream_t stream) {
  const float* x   = (const float*)d_in[0];
  const float* Wq  = (const float*)d_in[1];
  const float* bq  = (const float*)d_in[2];
  const float* Wk  = (const float*)d_in[3];
  const float* bk  = (const float*)d_in[4];
  const float* Wv  = (const float*)d_in[5];
  const float* bv  = (const float*)d_in[6];
  const float* Wo  = (const float*)d_in[7];
  const float* W1  = (const float*)d_in[8];
  const float* b1  = (const float*)d_in[9];
  const float* W2  = (const float*)d_in[10];
  const float* b2  = (const float*)d_in[11];
  const float* g1  = (const float*)d_in[12];
  const float* be1 = (const float*)d_in[13];
  const float* g2  = (const float*)d_in[14];
  const float* be2 = (const float*)d_in[15];

  char* ws = (char*)d_ws;
  size_t off = 0;
  auto alloc = [&](size_t bytes) { char* p = ws + off; off += (bytes + 255) & ~(size_t)255; return p; };
  unsigned short* WqkvT = (unsigned short*)alloc((size_t)3072 * 1024 * 2);
  unsigned short* WoT   = (unsigned short*)alloc((size_t)1024 * 1024 * 2);
  unsigned short* W1T   = (unsigned short*)alloc((size_t)4096 * 1024 * 2);
  unsigned short* W2T   = (unsigned short*)alloc((size_t)1024 * 4096 * 2);
  float*          bqkv  = (float*)alloc((size_t)3072 * 4);
  unsigned short* normed = (unsigned short*)alloc((size_t)NROWS * 1024 * 2);
  unsigned short* qkvbuf = (unsigned short*)alloc((size_t)NROWS * 4096 * 2);
  unsigned short* attnb  = (unsigned short*)alloc((size_t)NROWS * 1024 * 2);
  float*          x1     = (float*)alloc((size_t)NROWS * 1024 * 4);

  const dim3 tb(32, 8);
  transpose_cvt<<<dim3(32, 32), tb, 0, stream>>>(Wq, WqkvT, 1024, 1024);
  transpose_cvt<<<dim3(32, 32), tb, 0, stream>>>(Wk, WqkvT + 1024 * 1024, 1024, 1024);
  transpose_cvt<<<dim3(32, 32), tb, 0, stream>>>(Wv, WqkvT + 2 * 1024 * 1024, 1024, 1024);
  transpose_cvt<<<dim3(32, 32), tb, 0, stream>>>(Wo, WoT, 1024, 1024);
  transpose_cvt<<<dim3(128, 32), tb, 0, stream>>>(W1, W1T, 1024, 4096);
  transpose_cvt<<<dim3(32, 128), tb, 0, stream>>>(W2, W2T, 4096, 1024);
  concat_bias<<<12, 256, 0, stream>>>(bq, bk, bv, bqkv);

  layernorm_k<<<NROWS, 256, 0, stream>>>(x, g1, be1, normed);
  gemm3_k<(EP_BIAS | EP_BF16 | EP_QSCALE)><<<dim3(24, 32), 512, 0, stream>>>(normed, WqkvT, bqkv, nullptr, qkvbuf, NROWS, 3072, 1024);
  attn_k<<<dim3(8, 64), 512, 0, stream>>>(qkvbuf, attnb);
  gemm3_k<EP_RES><<<dim3(8, 32), 512, 0, stream>>>(attnb, WoT, nullptr, x, x1, NROWS, 1024, 1024);
  layernorm_k<<<NROWS, 256, 0, stream>>>(x1, g2, be2, normed);
  gemm3_k<(EP_BIAS | EP_GELU | EP_BF16)><<<dim3(32, 32), 512, 0, stream>>>(normed, W1T, b1, nullptr, qkvbuf, NROWS, 4096, 1024);
  gemm3_k<(EP_BIAS | EP_RES)><<<dim3(8, 32), 512, 0, stream>>>(qkvbuf, W2T, b2, x1, d_out, NROWS, 1024, 4096);
}

// Round 6
// 523.068 us; speedup vs baseline: 1.1394x; 1.0366x over previous
//
#include <hip/hip_runtime.h>

#define SEQ 2048
#define NROWS 8192            // 4 * 2048
#define NH 16
#define DHEAD 64
#define QLD 3072              // q,k,v concatenated columns

typedef float f32x4 __attribute__((ext_vector_type(4)));
typedef __bf16 bf16x8 __attribute__((ext_vector_type(8)));

__device__ __forceinline__ unsigned short f2bf(float f) {
  union { float f; unsigned u; } v; v.f = f;
  unsigned r = v.u + 0x7fffu + ((v.u >> 16) & 1u);
  return (unsigned short)(r >> 16);
}

__device__ __forceinline__ void gl16(const void* g, void* l) {
  __builtin_amdgcn_global_load_lds((const __attribute__((address_space(1))) void*)g,
                                   (__attribute__((address_space(3))) void*)l, 16, 0, 0);
}

__device__ __forceinline__ float gelu_f(float x) {
  float t = 0.7978845608028654f * (x + 0.044715f * x * x * x);
  float e = __expf(2.0f * t);
  float th = 1.0f - 2.0f / (e + 1.0f);   // tanh(t), saturates cleanly
  return 0.5f * x * (1.0f + th);
}

#define CVTPK(dst, lo, hi) asm("v_cvt_pk_bf16_f32 %0, %1, %2" : "=v"(dst) : "v"(lo), "v"(hi))

#if __has_builtin(__builtin_amdgcn_permlane32_swap)
#define P32SWAP(a, b, x, y) { auto _t = __builtin_amdgcn_permlane32_swap((a), (b), false, false); (x) = _t[0]; (y) = _t[1]; }
#else
#define P32SWAP(a, b, x, y) { unsigned _as = (unsigned)__shfl_xor((int)(a), 32, 64); \
  unsigned _bs = (unsigned)__shfl_xor((int)(b), 32, 64); \
  (x) = (l < 32) ? (a) : _bs; (y) = (l < 32) ? _as : (b); }
#endif
#if __has_builtin(__builtin_amdgcn_permlane16_swap)
#define P16SWAP(a, b, x, y) { auto _t = __builtin_amdgcn_permlane16_swap((a), (b), false, false); (x) = _t[0]; (y) = _t[1]; }
#else
#define P16SWAP(a, b, x, y) { unsigned _as = (unsigned)__shfl_xor((int)(a), 16, 64); \
  unsigned _bs = (unsigned)__shfl_xor((int)(b), 16, 64); \
  (x) = (l & 16) ? _bs : (a); (y) = (l & 16) ? (b) : _as; }
#endif

#define MEMFENCE asm volatile("" ::: "memory")
#define BAR() do { MEMFENCE; __builtin_amdgcn_s_barrier(); MEMFENCE; } while (0)
#define WAIT_LGKM0 asm volatile("s_waitcnt lgkmcnt(0)" ::: "memory")
#define WAIT_VM8 asm volatile("s_waitcnt vmcnt(8)" ::: "memory")
#define WAIT_VM6 asm volatile("s_waitcnt vmcnt(6)" ::: "memory")
#define WAIT_VM0 asm volatile("s_waitcnt vmcnt(0)" ::: "memory")

// ---------------- transpose + fp32->bf16 convert: Wt[n][k] = W[k][n] ----------------
__global__ __launch_bounds__(256) void transpose_cvt(const float* __restrict__ W,
                                                     unsigned short* __restrict__ Wt,
                                                     int K, int N) {
  __shared__ float tile[32][33];
  const int tx = threadIdx.x, ty = threadIdx.y;
  const int n0 = blockIdx.x * 32, k0 = blockIdx.y * 32;
#pragma unroll
  for (int i = ty; i < 32; i += 8)
    tile[i][tx] = W[(size_t)(k0 + i) * N + n0 + tx];
  __syncthreads();
#pragma unroll
  for (int i = ty; i < 32; i += 8)
    Wt[(size_t)(n0 + i) * K + k0 + tx] = f2bf(tile[tx][i]);
}

__global__ __launch_bounds__(256) void concat_bias(const float* __restrict__ bq,
                                                   const float* __restrict__ bk,
                                                   const float* __restrict__ bv,
                                                   float* __restrict__ dst) {
  int i = blockIdx.x * 256 + threadIdx.x;
  if (i < 1024) dst[i] = bq[i];
  else if (i < 2048) dst[i] = bk[i - 1024];
  else if (i < 3072) dst[i] = bv[i - 2048];
}

// ---------------- LayerNorm: fp32 in -> bf16 out, one block per 1024-row ----------------
__global__ __launch_bounds__(256) void layernorm_k(const float* __restrict__ x,
                                                   const float* __restrict__ g,
                                                   const float* __restrict__ b,
                                                   unsigned short* __restrict__ out) {
  const int row = blockIdx.x, tid = threadIdx.x;
  const float4 v = reinterpret_cast<const float4*>(x + (size_t)row * 1024)[tid];
  float s = v.x + v.y + v.z + v.w;
  float s2 = v.x * v.x + v.y * v.y + v.z * v.z + v.w * v.w;
#pragma unroll
  for (int d = 1; d < 64; d <<= 1) { s += __shfl_xor(s, d, 64); s2 += __shfl_xor(s2, d, 64); }
  __shared__ float ls[4], ls2[4];
  const int w = tid >> 6;
  if ((tid & 63) == 0) { ls[w] = s; ls2[w] = s2; }
  __syncthreads();
  s = ls[0] + ls[1] + ls[2] + ls[3];
  s2 = ls2[0] + ls2[1] + ls2[2] + ls2[3];
  const float mu = s * (1.0f / 1024.0f);
  const float var = s2 * (1.0f / 1024.0f) - mu * mu;
  const float rstd = rsqrtf(var + 1e-6f);
  const float4 gv = reinterpret_cast<const float4*>(g)[tid];
  const float4 bv = reinterpret_cast<const float4*>(b)[tid];
  ushort4 o;
  o.x = f2bf((v.x - mu) * rstd * gv.x + bv.x);
  o.y = f2bf((v.y - mu) * rstd * gv.y + bv.y);
  o.z = f2bf((v.z - mu) * rstd * gv.z + bv.z);
  o.w = f2bf((v.w - mu) * rstd * gv.w + bv.w);
  reinterpret_cast<ushort4*>(out + (size_t)row * 1024)[tid] = o;
}

enum { EP_BIAS = 1, EP_RES = 2, EP_GELU = 4, EP_BF16 = 8, EP_QSCALE = 16 };

// ---------------- Big GEMM: BM=256, BN=256, BK=64, wave-tile 128x64 (HK geometry) -----
// 512 threads (8 waves, 2M x 4N). 2-slot LDS (2 x 64KB = 128KB, 1 block/CU).
// Per tile: stage(t+1) FIRST, then vmcnt(8) [only t+1's 8 loads younger => tile t
// landed], barrier, 24 ds_read_b128 burst (compiler inserts exact lgkm waits),
// 64 MFMA, trailing barrier. Counted vmcnt never drains mid-loop (T4).
// XOR-swizzled LDS (T2), setprio (T5), XCD-chunked block order (T1).
template <int E>
__global__ __launch_bounds__(512, 1) void gemm2_k(const unsigned short* __restrict__ A,
                                                  const unsigned short* __restrict__ Bt,
                                                  const float* __restrict__ bias,
                                                  const float* __restrict__ resid,
                                                  void* __restrict__ out,
                                                  int M, int N, int K) {
  __shared__ __align__(16) unsigned short Ls[2][32768];  // per slot: A 32KB | B 32KB
  const int tid = threadIdx.x;
  const int l = tid & 63, w = tid >> 6;
  const int lr = l & 15, lg = l >> 4;
  const int wr = w >> 2, wc = w & 3;

  const int gx = gridDim.x;
  const int nwg = gx * gridDim.y;
  int lin = blockIdx.y * gx + blockIdx.x;
  lin = (lin & 7) * (nwg >> 3) + (lin >> 3);
  const int bn = lin % gx, bm = lin / gx;

  const unsigned short* Ab = A + (size_t)(bm * 256) * K;
  const unsigned short* Bb = Bt + (size_t)(bn * 256) * K;
  const int NK = K >> 6;

  const int srow8 = l >> 3;
  const int sslot = (l & 7) ^ srow8;

  auto stage = [&](int slot, int t) {
    char* base = (char*)(&Ls[slot][0]);
    const char* a0 = (const char*)(Ab + (size_t)srow8 * K + t * 64) + sslot * 16;
    const char* b0 = (const char*)(Bb + (size_t)srow8 * K + t * 64) + sslot * 16;
    const size_t rs8 = (size_t)8 * K * 2;
#pragma unroll
    for (int i = 0; i < 4; ++i)
      gl16(a0 + (size_t)(8 * i + w) * rs8, base + (8 * i + w) * 1024 + l * 16);
#pragma unroll
    for (int i = 0; i < 4; ++i)
      gl16(b0 + (size_t)(8 * i + w) * rs8, base + 32768 + (8 * i + w) * 1024 + l * 16);
  };
  auto rd = [&](const char* base, int r, int ks) {
    return *reinterpret_cast<const bf16x8*>(base + r * 128 + (((ks << 2) + lg) ^ (r & 7)) * 16);
  };

  f32x4 acc[8][4];
#pragma unroll
  for (int m = 0; m < 8; ++m)
#pragma unroll
    for (int n = 0; n < 4; ++n) acc[m][n] = 0.0f;

  stage(0, 0);

  for (int t = 0; t < NK; ++t) {
    const int cs = t & 1, nb = cs ^ 1;
    if (t + 1 < NK) { stage(nb, t + 1); WAIT_VM8; } else { WAIT_VM0; }
    BAR();

    const char* Ac = (const char*)(&Ls[cs][0]);
    const char* Bc = Ac + 32768;
    bf16x8 bf[4][2], a0[4][2], a1[4][2];
#pragma unroll
    for (int ni = 0; ni < 4; ++ni)
#pragma unroll
      for (int ks = 0; ks < 2; ++ks) bf[ni][ks] = rd(Bc, wc * 64 + ni * 16 + lr, ks);
#pragma unroll
    for (int mi = 0; mi < 4; ++mi)
#pragma unroll
      for (int ks = 0; ks < 2; ++ks) a0[mi][ks] = rd(Ac, wr * 128 + mi * 16 + lr, ks);
#pragma unroll
    for (int mi = 0; mi < 4; ++mi)
#pragma unroll
      for (int ks = 0; ks < 2; ++ks) a1[mi][ks] = rd(Ac, wr * 128 + (4 + mi) * 16 + lr, ks);

    __builtin_amdgcn_s_setprio(1);
#pragma unroll
    for (int mi = 0; mi < 4; ++mi)
#pragma unroll
      for (int ni = 0; ni < 4; ++ni)
#pragma unroll
        for (int ks = 0; ks < 2; ++ks)
          acc[mi][ni] = __builtin_amdgcn_mfma_f32_16x16x32_bf16(a0[mi][ks], bf[ni][ks], acc[mi][ni], 0, 0, 0);
#pragma unroll
    for (int mi = 0; mi < 4; ++mi)
#pragma unroll
      for (int ni = 0; ni < 4; ++ni)
#pragma unroll
        for (int ks = 0; ks < 2; ++ks)
          acc[4 + mi][ni] = __builtin_amdgcn_mfma_f32_16x16x32_bf16(a1[mi][ks], bf[ni][ks], acc[4 + mi][ni], 0, 0, 0);
    __builtin_amdgcn_s_setprio(0);
    BAR();
  }

  const int row0 = bm * 256 + wr * 128;
  const int col0 = bn * 256 + wc * 64;
#pragma unroll
  for (int m = 0; m < 8; ++m) {
#pragma unroll
    for (int n = 0; n < 4; ++n) {
      const int col = col0 + n * 16 + lr;
      float bc = 0.0f;
      if (E & EP_BIAS) bc = bias[col];
#pragma unroll
      for (int j = 0; j < 4; ++j) {
        const int row = row0 + m * 16 + lg * 4 + j;
        float v = acc[m][n][j] + bc;
        if (E & EP_RES) v += resid[(size_t)row * N + col];
        if (E & EP_GELU) v = gelu_f(v);
        if (E & EP_QSCALE) { if (col < 1024) v *= 0.18033688011112042f; }  // 0.125*log2(e)
        if (E & EP_BF16) ((unsigned short*)out)[(size_t)row * N + col] = f2bf(v);
        else ((float*)out)[(size_t)row * N + col] = v;
      }
    }
  }
}

// ---------------- 3-slot ring GEMM (BM=256, BN=128, wave 64x64) — Wo / FF2 ----------
template <int E>
__global__ __launch_bounds__(512) void gemm3_k(const unsigned short* __restrict__ A,
                                               const unsigned short* __restrict__ Bt,
                                               const float* __restrict__ bias,
                                               const float* __restrict__ resid,
                                               void* __restrict__ out,
                                               int M, int N, int K) {
  __shared__ __align__(16) unsigned short Ls[3][24576];  // per slot: A 32KB | B 16KB
  const int tid = threadIdx.x;
  const int l = tid & 63, w = tid >> 6;
  const int lr = l & 15, lg = l >> 4;
  const int wr = w >> 1, wc = w & 1;

  const int gx = gridDim.x;
  const int nwg = gx * gridDim.y;
  int lin = blockIdx.y * gx + blockIdx.x;
  lin = (lin & 7) * (nwg >> 3) + (lin >> 3);
  const int bn = lin % gx, bm = lin / gx;

  const unsigned short* Ab = A + (size_t)(bm * 256) * K;
  const unsigned short* Bb = Bt + (size_t)(bn * 128) * K;
  const int NK = K >> 6;

  const int srow8 = l >> 3;
  const int sslot = (l & 7) ^ srow8;
  const size_t rs8 = (size_t)8 * K * 2;

  auto stage = [&](int slot, int t) {
    if (t >= NK) return;
    char* base = (char*)(&Ls[slot][0]);
    const char* a0 = (const char*)(Ab + (size_t)srow8 * K + t * 64) + sslot * 16;
    const char* b0 = (const char*)(Bb + (size_t)srow8 * K + t * 64) + sslot * 16;
    gl16(a0 + (size_t)w * rs8,        base + w * 1024 + l * 16);
    gl16(a0 + (size_t)(8 + w) * rs8,  base + (8 + w) * 1024 + l * 16);
    gl16(a0 + (size_t)(16 + w) * rs8, base + (16 + w) * 1024 + l * 16);
    gl16(a0 + (size_t)(24 + w) * rs8, base + (24 + w) * 1024 + l * 16);
    gl16(b0 + (size_t)w * rs8,        base + 32768 + w * 1024 + l * 16);
    gl16(b0 + (size_t)(8 + w) * rs8,  base + 32768 + (8 + w) * 1024 + l * 16);
  };
  auto rd = [&](const char* base, int r, int ks) {
    return *reinterpret_cast<const bf16x8*>(base + r * 128 + (((ks << 2) + lg) ^ (r & 7)) * 16);
  };

  f32x4 acc[4][4];
#pragma unroll
  for (int m = 0; m < 4; ++m)
#pragma unroll
    for (int n = 0; n < 4; ++n) acc[m][n] = 0.0f;

  stage(0, 0);
  stage(1, 1);
  int cs = 0, ss = 2;

  for (int t = 0; t < NK; ++t) {
    if (t + 1 < NK) { WAIT_VM6; } else { WAIT_VM0; }
    BAR();
    stage(ss, t + 2);

    const char* Ac = (const char*)(&Ls[cs][0]);
    const char* Bc = Ac + 32768;
    bf16x8 af[4][2], bf[4][2];
#pragma unroll
    for (int mi = 0; mi < 4; ++mi)
#pragma unroll
      for (int ks = 0; ks < 2; ++ks) af[mi][ks] = rd(Ac, wr * 64 + mi * 16 + lr, ks);
#pragma unroll
    for (int ni = 0; ni < 4; ++ni)
#pragma unroll
      for (int ks = 0; ks < 2; ++ks) bf[ni][ks] = rd(Bc, wc * 64 + ni * 16 + lr, ks);

    __builtin_amdgcn_s_setprio(1);
#pragma unroll
    for (int mi = 0; mi < 4; ++mi)
#pragma unroll
      for (int ni = 0; ni < 4; ++ni)
#pragma unroll
        for (int ks = 0; ks < 2; ++ks)
          acc[mi][ni] = __builtin_amdgcn_mfma_f32_16x16x32_bf16(af[mi][ks], bf[ni][ks], acc[mi][ni], 0, 0, 0);
    __builtin_amdgcn_s_setprio(0);
    WAIT_LGKM0;

    cs = (cs == 2) ? 0 : cs + 1;
    ss = (ss == 2) ? 0 : ss + 1;
  }

  const int row0 = bm * 256 + wr * 64;
  const int col0 = bn * 128 + wc * 64;
#pragma unroll
  for (int m = 0; m < 4; ++m) {
#pragma unroll
    for (int n = 0; n < 4; ++n) {
      const int col = col0 + n * 16 + lr;
      float bc = 0.0f;
      if (E & EP_BIAS) bc = bias[col];
#pragma unroll
      for (int j = 0; j < 4; ++j) {
        const int row = row0 + m * 16 + lg * 4 + j;
        float v = acc[m][n][j] + bc;
        if (E & EP_RES) v += resid[(size_t)row * N + col];
        if (E & EP_GELU) v = gelu_f(v);
        if (E & EP_QSCALE) { if (col < 1024) v *= 0.18033688011112042f; }
        if (E & EP_BF16) ((unsigned short*)out)[(size_t)row * N + col] = f2bf(v);
        else ((float*)out)[(size_t)row * N + col] = v;
      }
    }
  }
}

// ---------------- Flash attention (R3 structure): causal, 16 heads, Dh=64, KVBLK=64 --
// S^T = mfma(K,Q), lane owns one q-row's k-strip (log2 domain). Lane-local softmax
// + defer-max (THR=8) + exp2f. In-register P->B-frag via cvt_pk + permlane swaps.
// O^T = mfma(V^T, P^T). Blocks pair (qt, 15-qt): every block 34 k-tile iterations.
__global__ __launch_bounds__(512, 4) void attn_k(const unsigned short* __restrict__ qkv,
                                                 unsigned short* __restrict__ out) {
  __shared__ __align__(16) unsigned short Kl[2][4096];  // [64 s][128B], swizzled
  __shared__ __align__(16) unsigned short Vt[2][4096];  // V^T [64 dh][128B], swizzled
  const int tid = threadIdx.x;
  const int l = tid & 63, w = tid >> 6;
  const int lr = l & 15, lg = l >> 4;
  const int bh = blockIdx.y;
  const int b = bh >> 4, h = bh & 15;
  const size_t rowbase = (size_t)b * SEQ;
  char* klb = (char*)Kl;
  char* vtb = (char*)Vt;
  const int sg = tid & 15, dhg = tid >> 4;  // V staging roles (tid < 256)

  auto stageK = [&](int buf, int kb2) {
    const int r = (w << 3) + (l >> 3);
    const char* src = (const char*)(qkv + (rowbase + kb2 + r) * QLD + 1024 + h * 64)
                      + 16 * ((l & 7) ^ (l >> 3));
    gl16(src, klb + buf * 8192 + (w << 10) + (l << 4));
  };
  auto loadV = [&](int kb2, uint2* vr) {
    if (tid < 256) {
#pragma unroll
      for (int i = 0; i < 4; ++i)
        vr[i] = *reinterpret_cast<const uint2*>(
            qkv + (rowbase + kb2 + sg * 4 + i) * QLD + 2048 + h * 64 + dhg * 4);
    }
  };
  auto writeV = [&](int buf, const uint2* vr) {
    if (tid < 256) {
      char* vb = vtb + buf * 8192;
#pragma unroll
      for (int jj = 0; jj < 4; ++jj) {
        const int dh = dhg * 4 + jj;
        unsigned a0 = (jj < 2) ? vr[0].x : vr[0].y;
        unsigned a1 = (jj < 2) ? vr[1].x : vr[1].y;
        unsigned a2 = (jj < 2) ? vr[2].x : vr[2].y;
        unsigned a3 = (jj < 2) ? vr[3].x : vr[3].y;
        unsigned s01, s23;
        if (jj & 1) {
          s01 = (a0 >> 16) | (a1 & 0xffff0000u);
          s23 = (a2 >> 16) | (a3 & 0xffff0000u);
        } else {
          s01 = (a0 & 0xffffu) | (a1 << 16);
          s23 = (a2 & 0xffffu) | (a3 << 16);
        }
        const int bo = (dh * 128 + sg * 8) ^ ((dh & 7) << 4);
        uint2 p; p.x = s01; p.y = s23;
        *reinterpret_cast<uint2*>(vb + bo) = p;
      }
    }
  };

#pragma unroll 1
  for (int seg = 0; seg < 2; ++seg) {
    const int qt = seg ? (15 - blockIdx.x) : blockIdx.x;
    const int q0 = qt << 7;
    const int ktmax = 2 * qt + 1;
    const int qwmin = q0 + w * 16;
    const int qrow = qwmin + lr;

    bf16x8 qf[2];
#pragma unroll
    for (int ks = 0; ks < 2; ++ks)
      qf[ks] = *reinterpret_cast<const bf16x8*>(
          qkv + (rowbase + qrow) * QLD + h * 64 + ks * 32 + lg * 8);

    f32x4 oacc[4];
#pragma unroll
    for (int n = 0; n < 4; ++n) oacc[n] = 0.0f;
    float mrun = -1e30f, lrun = 0.0f;

    {  // prologue: stage kt=0 into buffer 0
      stageK(0, 0);
      uint2 vr0[4];
      loadV(0, vr0);
      writeV(0, vr0);
    }
    __syncthreads();

#pragma unroll 1
    for (int kt = 0; kt <= ktmax; ++kt) {
      const int cur = kt & 1, nb = cur ^ 1;
      const int kb = kt << 6;
      const bool more = kt < ktmax;
      const bool active = kb <= qwmin + 15;  // wave-uniform: skip fully-masked tiles
      uint2 vr[4];
      if (more) { stageK(nb, (kt + 1) << 6); loadV((kt + 1) << 6, vr); }

      f32x4 sacc[4];
      if (active) {
#pragma unroll
        for (int ni = 0; ni < 4; ++ni) sacc[ni] = 0.0f;
        const char* kc = klb + cur * 8192;
        __builtin_amdgcn_s_setprio(1);
#pragma unroll
        for (int ks = 0; ks < 2; ++ks) {
#pragma unroll
          for (int ni = 0; ni < 4; ++ni) {
            const int r = ni * 16 + lr;
            const int bo = (r * 128 + ks * 64 + lg * 16) ^ ((lr & 7) << 4);
            bf16x8 kf = *reinterpret_cast<const bf16x8*>(kc + bo);
            sacc[ni] = __builtin_amdgcn_mfma_f32_16x16x32_bf16(kf, qf[ks], sacc[ni], 0, 0, 0);
          }
        }
        __builtin_amdgcn_s_setprio(0);

        // ---- causal mask (log2-domain scores) ----
        if (kb + 63 > qwmin) {
#pragma unroll
          for (int ni = 0; ni < 4; ++ni)
#pragma unroll
            for (int j = 0; j < 4; ++j)
              if (kb + ni * 16 + lg * 4 + j > qrow) sacc[ni][j] = -1e30f;
        }

        // ---- online softmax: lane-local + 2 shuffles, defer-max (THR=8) ----
        float pm = sacc[0][0];
#pragma unroll
        for (int ni = 0; ni < 4; ++ni)
#pragma unroll
          for (int j = 0; j < 4; ++j) pm = fmaxf(pm, sacc[ni][j]);
        pm = fmaxf(pm, __shfl_xor(pm, 16, 64));
        pm = fmaxf(pm, __shfl_xor(pm, 32, 64));
        if (!__all(pm <= mrun + 8.0f)) {
          const float mnew = fmaxf(mrun, pm);
          const float alpha = exp2f(mrun - mnew);
          mrun = mnew;
          lrun *= alpha;
#pragma unroll
          for (int n = 0; n < 4; ++n) oacc[n] *= alpha;
        }
        float rs = 0.0f;
#pragma unroll
        for (int ni = 0; ni < 4; ++ni)
#pragma unroll
          for (int j = 0; j < 4; ++j) {
            const float p = exp2f(sacc[ni][j] - mrun);
            sacc[ni][j] = p;
            rs += p;
          }
        rs += __shfl_xor(rs, 16, 64);
        rs += __shfl_xor(rs, 32, 64);
        lrun += rs;
      }

      if (more) writeV(nb, vr);  // overlapped: HBM latency hid under QK+softmax

      if (active) {
        // ---- O^T += V^T * P^T : build B-frags in-register ----
        const char* vc = vtb + cur * 8192;
#pragma unroll
        for (int ks2 = 0; ks2 < 2; ++ks2) {
          unsigned U0, U1, U2, U3, C0, C1, W0, W1, W2, W3;
          CVTPK(U0, sacc[2 * ks2][0], sacc[2 * ks2][1]);
          CVTPK(U1, sacc[2 * ks2][2], sacc[2 * ks2][3]);
          CVTPK(U2, sacc[2 * ks2 + 1][0], sacc[2 * ks2 + 1][1]);
          CVTPK(U3, sacc[2 * ks2 + 1][2], sacc[2 * ks2 + 1][3]);
          P32SWAP(U0, U2, C0, C1);
          P16SWAP(C0, C1, W0, W2);
          P32SWAP(U1, U3, C0, C1);
          P16SWAP(C0, C1, W1, W3);
          union { uint4 u; bf16x8 v; } pu;
          pu.u = make_uint4(W0, W1, W2, W3);
          __builtin_amdgcn_s_setprio(1);
#pragma unroll
          for (int n = 0; n < 4; ++n) {
            const int r = n * 16 + lr;
            const int bo = (r * 128 + ks2 * 64 + lg * 16) ^ ((lr & 7) << 4);
            bf16x8 vf = *reinterpret_cast<const bf16x8*>(vc + bo);
            oacc[n] = __builtin_amdgcn_mfma_f32_16x16x32_bf16(vf, pu.v, oacc[n], 0, 0, 0);
          }
          __builtin_amdgcn_s_setprio(0);
        }
      }
      __syncthreads();
    }

    // ---- finalize ----
    const float inv = 1.0f / lrun;
#pragma unroll
    for (int n = 0; n < 4; ++n) {
      ushort4 o;
      o.x = f2bf(oacc[n][0] * inv);
      o.y = f2bf(oacc[n][1] * inv);
      o.z = f2bf(oacc[n][2] * inv);
      o.w = f2bf(oacc[n][3] * inv);
      *reinterpret_cast<ushort4*>(out + (rowbase + qrow) * 1024 + h * 64 + n * 16 + lg * 4) = o;
    }
  }
}

// ---------------- host ----------------
extern "C" void kernel_launch(void* const* d_in, const int* in_sizes, int n_in,
                              void* d_out, int out_size, void* d_ws, size_t ws_size,
                              hipStream_t stream) {
  const float* x   = (const float*)d_in[0];
  const float* Wq  = (const float*)d_in[1];
  const float* bq  = (const float*)d_in[2];
  const float* Wk  = (const float*)d_in[3];
  const float* bk  = (const float*)d_in[4];
  const float* Wv  = (const float*)d_in[5];
  const float* bv  = (const float*)d_in[6];
  const float* Wo  = (const float*)d_in[7];
  const float* W1  = (const float*)d_in[8];
  const float* b1  = (const float*)d_in[9];
  const float* W2  = (const float*)d_in[10];
  const float* b2  = (const float*)d_in[11];
  const float* g1  = (const float*)d_in[12];
  const float* be1 = (const float*)d_in[13];
  const float* g2  = (const float*)d_in[14];
  const float* be2 = (const float*)d_in[15];

  char* ws = (char*)d_ws;
  size_t off = 0;
  auto alloc = [&](size_t bytes) { char* p = ws + off; off += (bytes + 255) & ~(size_t)255; return p; };
  unsigned short* WqkvT = (unsigned short*)alloc((size_t)3072 * 1024 * 2);
  unsigned short* WoT   = (unsigned short*)alloc((size_t)1024 * 1024 * 2);
  unsigned short* W1T   = (unsigned short*)alloc((size_t)4096 * 1024 * 2);
  unsigned short* W2T   = (unsigned short*)alloc((size_t)1024 * 4096 * 2);
  float*          bqkv  = (float*)alloc((size_t)3072 * 4);
  unsigned short* normed = (unsigned short*)alloc((size_t)NROWS * 1024 * 2);
  unsigned short* qkvbuf = (unsigned short*)alloc((size_t)NROWS * 4096 * 2);
  unsigned short* attnb  = (unsigned short*)alloc((size_t)NROWS * 1024 * 2);
  float*          x1     = (float*)alloc((size_t)NROWS * 1024 * 4);

  const dim3 tb(32, 8);
  transpose_cvt<<<dim3(32, 32), tb, 0, stream>>>(Wq, WqkvT, 1024, 1024);
  transpose_cvt<<<dim3(32, 32), tb, 0, stream>>>(Wk, WqkvT + 1024 * 1024, 1024, 1024);
  transpose_cvt<<<dim3(32, 32), tb, 0, stream>>>(Wv, WqkvT + 2 * 1024 * 1024, 1024, 1024);
  transpose_cvt<<<dim3(32, 32), tb, 0, stream>>>(Wo, WoT, 1024, 1024);
  transpose_cvt<<<dim3(128, 32), tb, 0, stream>>>(W1, W1T, 1024, 4096);
  transpose_cvt<<<dim3(32, 128), tb, 0, stream>>>(W2, W2T, 4096, 1024);
  concat_bias<<<12, 256, 0, stream>>>(bq, bk, bv, bqkv);

  layernorm_k<<<NROWS, 256, 0, stream>>>(x, g1, be1, normed);
  gemm2_k<(EP_BIAS | EP_BF16 | EP_QSCALE)><<<dim3(12, 32), 512, 0, stream>>>(normed, WqkvT, bqkv, nullptr, qkvbuf, NROWS, 3072, 1024);
  attn_k<<<dim3(8, 64), 512, 0, stream>>>(qkvbuf, attnb);
  gemm3_k<EP_RES><<<dim3(8, 32), 512, 0, stream>>>(attnb, WoT, nullptr, x, x1, NROWS, 1024, 1024);
  layernorm_k<<<NROWS, 256, 0, stream>>>(x1, g2, be2, normed);
  gemm2_k<(EP_BIAS | EP_GELU | EP_BF16)><<<dim3(16, 32), 512, 0, stream>>>(normed, W1T, b1, nullptr, qkvbuf, NROWS, 4096, 1024);
  gemm3_k<(EP_BIAS | EP_RES)><<<dim3(8, 32), 512, 0, stream>>>(qkvbuf, W2T, b2, x1, d_out, NROWS, 1024, 4096);
}